// Round 1
// baseline (1213.988 us; speedup 1.0000x reference)
//
#include <hip/hip_runtime.h>
#include <cstdint>

// Problem constants: B=4, C=feat=64, N=H*W=4096.
#define BB 4
#define CC 64
#define NN 4096
#define NWRD 64          // 4096 bits / 64 per mask row
#define TAU 0.005f
#define EPSN 1e-5f
#define MSPLITS 4
#define MCHUNK (NN / MSPLITS)   // 1024 m per split

// ---------------- K1: transpose x[B][C][N] -> xt[B*N][C], rnorm = 1/||row|| ----
__global__ __launch_bounds__(256) void k_transpose(const float* __restrict__ x,
                                                   float* __restrict__ xt,
                                                   float* __restrict__ rnorm) {
    int lane = threadIdx.x & 63;
    int gw = blockIdx.x * 4 + (threadIdx.x >> 6);   // row id in [0, B*N)
    int b = gw >> 12;
    int n = gw & (NN - 1);
    float v = x[((size_t)(b * CC + lane)) * NN + n];
    xt[((size_t)gw) * CC + lane] = v;
    float s = v * v;
    #pragma unroll
    for (int off = 32; off; off >>= 1) s += __shfl_xor(s, off, 64);
    if (lane == 0) rnorm[gw] = rsqrtf(s);
}

// ---------------- K2: correlation -> binary adjacency bitmask --------------------
// Wave owns 64 consecutive m (lane=m), loops 256 n with wave-uniform row loads.
__global__ __launch_bounds__(256) void k_corr(const float* __restrict__ xt,
                                              const float* __restrict__ rnorm,
                                              unsigned long long* __restrict__ mask) {
    int lane = threadIdx.x & 63;
    int wave = threadIdx.x >> 6;
    int b = blockIdx.z;
    int mblock = blockIdx.x;            // 0..15
    int n0 = blockIdx.y * 256;          // 0..15
    int m = mblock * 256 + wave * 64 + lane;
    const float4* xmp = (const float4*)(xt + ((size_t)(b * NN + m)) * CC);
    float4 xm[16];
    #pragma unroll
    for (int i = 0; i < 16; ++i) xm[i] = xmp[i];
    float rm = rnorm[b * NN + m];
    int word_idx = mblock * 4 + wave;
    for (int n = n0; n < n0 + 256; ++n) {
        const float4* xnp = (const float4*)(xt + ((size_t)(b * NN + n)) * CC);
        float rn = rnorm[b * NN + n];
        float4 acc = make_float4(0.f, 0.f, 0.f, 0.f);
        #pragma unroll
        for (int i = 0; i < 16; ++i) {
            float4 a = xnp[i];
            acc.x += a.x * xm[i].x; acc.y += a.y * xm[i].y;
            acc.z += a.z * xm[i].z; acc.w += a.w * xm[i].w;
        }
        float dot = (acc.x + acc.y) + (acc.z + acc.w);
        int bit = (dot * rm * rn) > TAU;
        unsigned long long bal = __ballot(bit);
        if (lane == 0) mask[((size_t)(b * NN + n)) * NWRD + word_idx] = bal;
    }
}

// ---------------- K3: deg -> dinv = 1/sqrt(deg) ---------------------------------
__global__ __launch_bounds__(256) void k_deg(const unsigned long long* __restrict__ mask,
                                             float* __restrict__ dinv) {
    int lane = threadIdx.x & 63;
    int gw = blockIdx.x * 4 + (threadIdx.x >> 6);   // row id
    unsigned long long w = mask[(size_t)gw * NWRD + lane];
    float cnt = (float)__popcll(w);
    #pragma unroll
    for (int off = 32; off; off >>= 1) cnt += __shfl_xor(cnt, off, 64);
    if (lane == 0) dinv[gw] = rsqrtf(cnt);
}

// ---------------- K4: y[row][c] = dinv[row] * xin[row][c] -----------------------
__global__ __launch_bounds__(256) void k_scale(const float* __restrict__ xin,
                                               const float* __restrict__ dinv,
                                               float* __restrict__ y) {
    int idx = blockIdx.x * blockDim.x + threadIdx.x;     // float4 index
    float4 v = ((const float4*)xin)[idx];
    float d = dinv[idx >> 4];                            // 16 float4 per row
    ((float4*)y)[idx] = make_float4(v.x * d, v.y * d, v.z * d, v.w * d);
}

// ---------------- K5a: masked diffusion partial sums ----------------------------
// lane = n (64 rows per wave). Per m: wave-uniform y row + per-lane bit ->
// exec-masked adds: ~1 VALU instr per 64 accumulated channels.
__global__ __launch_bounds__(64) void k_diffuse(const float* __restrict__ y,
                                                const unsigned long long* __restrict__ mask,
                                                float* __restrict__ plx) {
    int lane = threadIdx.x & 63;
    int b = blockIdx.z;
    int split = blockIdx.y;
    int n = blockIdx.x * 64 + lane;
    const unsigned long long* mrow = mask + ((size_t)(b * NN + n)) * NWRD;
    float acc[64];
    #pragma unroll
    for (int c = 0; c < 64; ++c) acc[c] = 0.f;
    int mw0 = split * (MCHUNK / 64);
    for (int mw = mw0; mw < mw0 + MCHUNK / 64; ++mw) {
        unsigned long long wv = mrow[mw];                 // per-lane mask word
        const float* ybase = y + ((size_t)(b * NN) + (size_t)mw * 64) * CC;
        for (int j = 0; j < 64; ++j) {
            const float4* yr = (const float4*)(ybase + (size_t)j * CC);
            float4 yv[16];
            #pragma unroll
            for (int i = 0; i < 16; ++i) yv[i] = yr[i];   // wave-uniform loads
            if ((wv >> j) & 1ull) {
                #pragma unroll
                for (int i = 0; i < 16; ++i) {
                    acc[4*i+0] += yv[i].x; acc[4*i+1] += yv[i].y;
                    acc[4*i+2] += yv[i].z; acc[4*i+3] += yv[i].w;
                }
            }
        }
    }
    float4* o4 = (float4*)(plx + ((size_t)((split * BB + b) * NN + n)) * CC);
    #pragma unroll
    for (int i = 0; i < 16; ++i)
        o4[i] = make_float4(acc[4*i+0], acc[4*i+1], acc[4*i+2], acc[4*i+3]);
}

// ---------------- K5b: reduce partials, *dinv_n, @W, instance norm, relu --------
__global__ __launch_bounds__(256) void k_out(const float* __restrict__ plx,
                                             const float* __restrict__ dinv,
                                             const float* __restrict__ W,
                                             float* __restrict__ xout) {
    __shared__ float Ws[64 * 64];
    __shared__ float lxs[4][64];
    int lane = threadIdx.x & 63;
    int wave = threadIdx.x >> 6;
    int b = blockIdx.y;
    int n0 = blockIdx.x * 64;
    for (int i = threadIdx.x; i < 64 * 64; i += 256) Ws[i] = W[i];
    __syncthreads();
    for (int t = 0; t < 16; ++t) {
        int n = n0 + wave * 16 + t;
        size_t row = (size_t)(b * NN + n);
        float lx = 0.f;
        #pragma unroll
        for (int s = 0; s < MSPLITS; ++s)
            lx += plx[((size_t)(s * BB + b) * NN + n) * CC + lane];
        lx *= dinv[row];
        lxs[wave][lane] = lx;                 // same-wave LDS exchange (in-order DS)
        float h = 0.f;
        #pragma unroll
        for (int c = 0; c < 64; ++c) h += lxs[wave][c] * Ws[c * 64 + lane];
        float mean = h;
        #pragma unroll
        for (int off = 32; off; off >>= 1) mean += __shfl_xor(mean, off, 64);
        mean *= (1.f / 64.f);
        float dv = h - mean;
        float var = dv * dv;
        #pragma unroll
        for (int off = 32; off; off >>= 1) var += __shfl_xor(var, off, 64);
        var *= (1.f / 64.f);
        float o = dv * rsqrtf(var + EPSN);
        xout[row * CC + lane] = o > 0.f ? o : 0.f;
    }
}

extern "C" void kernel_launch(void* const* d_in, const int* in_sizes, int n_in,
                              void* d_out, int out_size, void* d_ws, size_t ws_size,
                              hipStream_t stream) {
    const float* x  = (const float*)d_in[0];
    const float* W0 = (const float*)d_in[1];
    const float* W1 = (const float*)d_in[2];
    float* out = (float*)d_out;

    char* ws = (char*)d_ws;
    // Workspace layout (~36.13 MiB total)
    float* xt    = (float*)(ws);                                  // 4 MiB
    float* x2    = (float*)(ws + ((size_t)4  << 20));             // 4 MiB
    float* ybuf  = (float*)(ws + ((size_t)8  << 20));             // 4 MiB
    float* plx   = (float*)(ws + ((size_t)12 << 20));             // 16 MiB
    unsigned long long* mask = (unsigned long long*)(ws + ((size_t)28 << 20)); // 8 MiB
    float* rnorm = (float*)(ws + ((size_t)36 << 20));             // 64 KiB
    float* dinv  = (float*)(ws + ((size_t)36 << 20) + ((size_t)64 << 10));     // 64 KiB

    // Build adjacency
    k_transpose<<<dim3(BB * NN / 4), 256, 0, stream>>>(x, xt, rnorm);
    k_corr<<<dim3(16, 16, BB), 256, 0, stream>>>(xt, rnorm, mask);
    k_deg<<<dim3(BB * NN / 4), 256, 0, stream>>>(mask, dinv);

    // Layer 1
    k_scale<<<dim3(BB * NN * CC / 4 / 256), 256, 0, stream>>>(xt, dinv, ybuf);
    k_diffuse<<<dim3(NN / 64, MSPLITS, BB), 64, 0, stream>>>(ybuf, mask, plx);
    k_out<<<dim3(NN / 64, BB), 256, 0, stream>>>(plx, dinv, W0, x2);

    // Layer 2
    k_scale<<<dim3(BB * NN * CC / 4 / 256), 256, 0, stream>>>(x2, dinv, ybuf);
    k_diffuse<<<dim3(NN / 64, MSPLITS, BB), 64, 0, stream>>>(ybuf, mask, plx);
    k_out<<<dim3(NN / 64, BB), 256, 0, stream>>>(plx, dinv, W1, out);
}

// Round 2
// 598.381 us; speedup vs baseline: 2.0288x; 2.0288x over previous
//
#include <hip/hip_runtime.h>
#include <hip/hip_bf16.h>
#include <cstdint>

// Problem constants: B=4, C=feat=64, N=H*W=4096.
#define BB 4
#define CC 64
#define NN 4096
#define NWRD 64          // 4096 bits / 64 per mask row
#define TAU 0.005f
#define EPSN 1e-5f

typedef __attribute__((ext_vector_type(8))) short short8;   // 8 bf16 (4 VGPRs)
typedef __attribute__((ext_vector_type(4))) float f32x4;

// ---------------- K1: transpose x[B][C][N] -> xt[B*N][C], rnorm = 1/||row|| ----
__global__ __launch_bounds__(256) void k_transpose(const float* __restrict__ x,
                                                   float* __restrict__ xt,
                                                   float* __restrict__ rnorm) {
    int lane = threadIdx.x & 63;
    int gw = blockIdx.x * 4 + (threadIdx.x >> 6);   // row id in [0, B*N)
    int b = gw >> 12;
    int n = gw & (NN - 1);
    float v = x[((size_t)(b * CC + lane)) * NN + n];
    xt[((size_t)gw) * CC + lane] = v;
    float s = v * v;
    #pragma unroll
    for (int off = 32; off; off >>= 1) s += __shfl_xor(s, off, 64);
    if (lane == 0) rnorm[gw] = rsqrtf(s);
}

// ---------------- K2: correlation -> binary adjacency bitmask -------------------
__global__ __launch_bounds__(256) void k_corr(const float* __restrict__ xt,
                                              const float* __restrict__ rnorm,
                                              unsigned long long* __restrict__ mask) {
    int lane = threadIdx.x & 63;
    int wave = threadIdx.x >> 6;
    int b = blockIdx.z;
    int mblock = blockIdx.x;            // 0..15
    int n0 = blockIdx.y * 256;          // 0..15
    int m = mblock * 256 + wave * 64 + lane;
    const float4* xmp = (const float4*)(xt + ((size_t)(b * NN + m)) * CC);
    float4 xm[16];
    #pragma unroll
    for (int i = 0; i < 16; ++i) xm[i] = xmp[i];
    float rm = rnorm[b * NN + m];
    int word_idx = mblock * 4 + wave;
    for (int n = n0; n < n0 + 256; ++n) {
        const float4* xnp = (const float4*)(xt + ((size_t)(b * NN + n)) * CC);
        float rn = rnorm[b * NN + n];
        float4 acc = make_float4(0.f, 0.f, 0.f, 0.f);
        #pragma unroll
        for (int i = 0; i < 16; ++i) {
            float4 a = xnp[i];
            acc.x += a.x * xm[i].x; acc.y += a.y * xm[i].y;
            acc.z += a.z * xm[i].z; acc.w += a.w * xm[i].w;
        }
        float dot = (acc.x + acc.y) + (acc.z + acc.w);
        int bit = (dot * rm * rn) > TAU;
        unsigned long long bal = __ballot(bit);
        if (lane == 0) mask[((size_t)(b * NN + n)) * NWRD + word_idx] = bal;
    }
}

// ---------------- K3: deg -> dinv = 1/sqrt(deg) ---------------------------------
__global__ __launch_bounds__(256) void k_deg(const unsigned long long* __restrict__ mask,
                                             float* __restrict__ dinv) {
    int lane = threadIdx.x & 63;
    int gw = blockIdx.x * 4 + (threadIdx.x >> 6);   // row id
    unsigned long long w = mask[(size_t)gw * NWRD + lane];
    float cnt = (float)__popcll(w);
    #pragma unroll
    for (int off = 32; off; off >>= 1) cnt += __shfl_xor(cnt, off, 64);
    if (lane == 0) dinv[gw] = rsqrtf(cnt);
}

// ---------------- K4: pack y = dinv.*xin into MFMA b-frag order, hi/lo bf16 -----
// yp[b][kt][c*32 + kin] = bf16(y[kt*32+kin][c]),  kt=0..127, kin=0..31
__global__ __launch_bounds__(256) void k_pack(const float* __restrict__ xin,
                                              const float* __restrict__ dinv,
                                              unsigned short* __restrict__ yph,
                                              unsigned short* __restrict__ ypl) {
    int t = threadIdx.x;
    int kt = blockIdx.x;                 // 0..127
    int b = blockIdx.y;
    int kin = t & 31;
    int m = kt * 32 + kin;
    float d = dinv[b * NN + m];
    size_t obase = (size_t)b * NN * CC + (size_t)kt * 2048;
    #pragma unroll
    for (int cg = 0; cg < 8; ++cg) {
        int c = cg * 8 + (t >> 5);
        float v = xin[((size_t)(b * NN + m)) * CC + c] * d;
        unsigned int u = __float_as_uint(v);
        unsigned int hb = (u + 0x7FFFu + ((u >> 16) & 1u)) >> 16;     // bf16 RNE
        float hif = __uint_as_float(hb << 16);
        float lo = v - hif;
        unsigned int u2 = __float_as_uint(lo);
        unsigned int lb = (u2 + 0x7FFFu + ((u2 >> 16) & 1u)) >> 16;
        yph[obase + c * 32 + kin] = (unsigned short)hb;
        ypl[obase + c * 32 + kin] = (unsigned short)lb;
    }
}

// ---------------- K5: MFMA diffusion GEMM + fused epilogue ----------------------
// S[n][c] = sum_m bit(n,m) * y(m,c)   (y = dinv.*x, hi+lo bf16 split)
// then lx = dinv_n * S; h = lx@W; instance-norm; relu -> out
__global__ __launch_bounds__(256) void k_gemm(const unsigned long long* __restrict__ mask,
                                              const unsigned short* __restrict__ yph,
                                              const unsigned short* __restrict__ ypl,
                                              const float* __restrict__ dinv,
                                              const float* __restrict__ W,
                                              float* __restrict__ out) {
    __shared__ float Ssh[64 * 64];
    int l = threadIdx.x & 63;
    int wv = threadIdx.x >> 6;
    int b = blockIdx.y;
    int n0 = blockIdx.x * 64;
    int q = l >> 4;                       // quad
    int lc = l & 15;
    int nrow = n0 + wv * 16 + lc;         // this lane's A row
    const unsigned long long* mrow = mask + ((size_t)(b * NN + nrow)) * NWRD;
    const unsigned short* bh = yph + (size_t)b * NN * CC;
    const unsigned short* bl = ypl + (size_t)b * NN * CC;

    f32x4 acc[4] = {f32x4{0,0,0,0}, f32x4{0,0,0,0}, f32x4{0,0,0,0}, f32x4{0,0,0,0}};

    for (int w64 = 0; w64 < 64; ++w64) {
        unsigned long long mword = mrow[w64];
        #pragma unroll
        for (int h = 0; h < 2; ++h) {
            unsigned int bits = (unsigned int)(mword >> (h * 32 + q * 8)) & 0xFFu;
            union { unsigned int u[4]; short8 v; } ua;
            ua.u[0] = ((bits & 1u)   ? 0x3F80u : 0u) | ((bits & 2u)   ? 0x3F800000u : 0u);
            ua.u[1] = ((bits & 4u)   ? 0x3F80u : 0u) | ((bits & 8u)   ? 0x3F800000u : 0u);
            ua.u[2] = ((bits & 16u)  ? 0x3F80u : 0u) | ((bits & 32u)  ? 0x3F800000u : 0u);
            ua.u[3] = ((bits & 64u)  ? 0x3F80u : 0u) | ((bits & 128u) ? 0x3F800000u : 0u);
            short8 afrag = ua.v;
            int kt = w64 * 2 + h;
            size_t bof = (size_t)kt * 2048 + q * 8;
            short8 bfh[4], bfl[4];
            #pragma unroll
            for (int t = 0; t < 4; ++t)
                bfh[t] = *(const short8*)(bh + bof + (size_t)(t * 16 + lc) * 32);
            #pragma unroll
            for (int t = 0; t < 4; ++t)
                bfl[t] = *(const short8*)(bl + bof + (size_t)(t * 16 + lc) * 32);
            #pragma unroll
            for (int t = 0; t < 4; ++t)
                acc[t] = __builtin_amdgcn_mfma_f32_16x16x32_bf16(afrag, bfh[t], acc[t], 0, 0, 0);
            #pragma unroll
            for (int t = 0; t < 4; ++t)
                acc[t] = __builtin_amdgcn_mfma_f32_16x16x32_bf16(afrag, bfl[t], acc[t], 0, 0, 0);
        }
    }

    // C/D layout: col = lane&15, row = (lane>>4)*4 + reg   [verified m89/m91]
    #pragma unroll
    for (int t = 0; t < 4; ++t)
        #pragma unroll
        for (int r = 0; r < 4; ++r)
            Ssh[(wv * 16 + q * 4 + r) * 64 + t * 16 + lc] = acc[t][r];

    float Wreg[64];
    #pragma unroll
    for (int c = 0; c < 64; ++c) Wreg[c] = W[c * 64 + l];
    __syncthreads();

    for (int t = 0; t < 16; ++t) {
        int n = n0 + wv * 16 + t;
        float dn = dinv[b * NN + n];
        float hsum = 0.f;
        #pragma unroll
        for (int c4 = 0; c4 < 16; ++c4) {
            float4 s4 = *(const float4*)&Ssh[(wv * 16 + t) * 64 + c4 * 4];
            hsum += s4.x * Wreg[c4 * 4 + 0] + s4.y * Wreg[c4 * 4 + 1]
                  + s4.z * Wreg[c4 * 4 + 2] + s4.w * Wreg[c4 * 4 + 3];
        }
        float hval = hsum * dn;
        float mean = hval;
        #pragma unroll
        for (int off = 32; off; off >>= 1) mean += __shfl_xor(mean, off, 64);
        mean *= (1.f / 64.f);
        float dv = hval - mean;
        float var = dv * dv;
        #pragma unroll
        for (int off = 32; off; off >>= 1) var += __shfl_xor(var, off, 64);
        var *= (1.f / 64.f);
        float o = dv * rsqrtf(var + EPSN);
        out[((size_t)(b * NN + n)) * CC + l] = o > 0.f ? o : 0.f;
    }
}

extern "C" void kernel_launch(void* const* d_in, const int* in_sizes, int n_in,
                              void* d_out, int out_size, void* d_ws, size_t ws_size,
                              hipStream_t stream) {
    const float* x  = (const float*)d_in[0];
    const float* W0 = (const float*)d_in[1];
    const float* W1 = (const float*)d_in[2];
    float* out = (float*)d_out;

    char* ws = (char*)d_ws;
    // Workspace layout (~20.2 MiB total)
    float* xt    = (float*)(ws);                                   // 4 MiB
    float* x2    = (float*)(ws + ((size_t)4  << 20));              // 4 MiB
    unsigned long long* mask = (unsigned long long*)(ws + ((size_t)8 << 20)); // 8 MiB
    unsigned short* yph = (unsigned short*)(ws + ((size_t)16 << 20));  // 2 MiB
    unsigned short* ypl = (unsigned short*)(ws + ((size_t)18 << 20));  // 2 MiB
    float* rnorm = (float*)(ws + ((size_t)20 << 20));              // 64 KiB
    float* dinv  = (float*)(ws + ((size_t)20 << 20) + ((size_t)64 << 10)); // 64 KiB

    // Build adjacency
    k_transpose<<<dim3(BB * NN / 4), 256, 0, stream>>>(x, xt, rnorm);
    k_corr<<<dim3(16, 16, BB), 256, 0, stream>>>(xt, rnorm, mask);
    k_deg<<<dim3(BB * NN / 4), 256, 0, stream>>>(mask, dinv);

    // Layer 1
    k_pack<<<dim3(128, BB), 256, 0, stream>>>(xt, dinv, yph, ypl);
    k_gemm<<<dim3(NN / 64, BB), 256, 0, stream>>>(mask, yph, ypl, dinv, W0, x2);

    // Layer 2
    k_pack<<<dim3(128, BB), 256, 0, stream>>>(x2, dinv, yph, ypl);
    k_gemm<<<dim3(NN / 64, BB), 256, 0, stream>>>(mask, yph, ypl, dinv, W1, out);
}

// Round 3
// 381.673 us; speedup vs baseline: 3.1807x; 1.5678x over previous
//
#include <hip/hip_runtime.h>
#include <hip/hip_bf16.h>
#include <cstdint>

// Problem constants: B=4, C=feat=64, N=H*W=4096.
#define BB 4
#define CC 64
#define NN 4096
#define NWRD 64          // 4096 bits / 64 per mask row
#define TAU 0.005f
#define EPSN 1e-5f

typedef __attribute__((ext_vector_type(8))) short short8;   // 8 bf16 (4 VGPRs)
typedef __attribute__((ext_vector_type(4))) float f32x4;

__device__ inline unsigned int bf16_rne(float v) {
    unsigned int u = __float_as_uint(v);
    return (u + 0x7FFFu + ((u >> 16) & 1u)) >> 16;
}

// ---------------- K1: transpose x[B][C][N] -> xt[B*N][C] fp32 + normalized bf16 hi/lo
__global__ __launch_bounds__(256) void k_transpose(const float* __restrict__ x,
                                                   float* __restrict__ xt,
                                                   unsigned short* __restrict__ ynh,
                                                   unsigned short* __restrict__ ynl) {
    int lane = threadIdx.x & 63;
    int gw = blockIdx.x * 4 + (threadIdx.x >> 6);   // row id in [0, B*N)
    int b = gw >> 12;
    int n = gw & (NN - 1);
    float v = x[((size_t)(b * CC + lane)) * NN + n];
    xt[((size_t)gw) * CC + lane] = v;
    float s = v * v;
    #pragma unroll
    for (int off = 32; off; off >>= 1) s += __shfl_xor(s, off, 64);
    float yv = v * rsqrtf(s);
    unsigned int hb = bf16_rne(yv);
    float lo = yv - __uint_as_float(hb << 16);
    unsigned int lb = bf16_rne(lo);
    ynh[(size_t)gw * CC + lane] = (unsigned short)hb;
    ynl[(size_t)gw * CC + lane] = (unsigned short)lb;
}

// ---------------- K2: MFMA correlation -> binary adjacency bitmask --------------
// G = Yn*Yn^T via bf16 hi/lo split (hh + hl + lh). Wave: 16 n x 64 m tile.
__global__ __launch_bounds__(256) void k_corr(const unsigned short* __restrict__ ynh,
                                              const unsigned short* __restrict__ ynl,
                                              unsigned long long* __restrict__ mask) {
    int l = threadIdx.x & 63;
    int wv = threadIdx.x >> 6;
    int lc = l & 15, q = l >> 4;
    int b = blockIdx.z;
    int n0 = blockIdx.x * 64 + wv * 16;
    int m0 = blockIdx.y * 64;
    const unsigned short* baseH = ynh + (size_t)b * NN * CC;
    const unsigned short* baseL = ynl + (size_t)b * NN * CC;
    short8 ah[2], al[2];
    #pragma unroll
    for (int ks = 0; ks < 2; ++ks) {
        size_t off = (size_t)(n0 + lc) * CC + ks * 32 + q * 8;
        ah[ks] = *(const short8*)(baseH + off);
        al[ks] = *(const short8*)(baseL + off);
    }
    unsigned long long bal[4][4];
    #pragma unroll
    for (int t = 0; t < 4; ++t) {
        f32x4 acc = {0.f, 0.f, 0.f, 0.f};
        #pragma unroll
        for (int ks = 0; ks < 2; ++ks) {
            size_t off = (size_t)(m0 + t * 16 + lc) * CC + ks * 32 + q * 8;
            short8 bh = *(const short8*)(baseH + off);
            short8 bl = *(const short8*)(baseL + off);
            acc = __builtin_amdgcn_mfma_f32_16x16x32_bf16(ah[ks], bh, acc, 0, 0, 0);
            acc = __builtin_amdgcn_mfma_f32_16x16x32_bf16(ah[ks], bl, acc, 0, 0, 0);
            acc = __builtin_amdgcn_mfma_f32_16x16x32_bf16(al[ks], bh, acc, 0, 0, 0);
        }
        #pragma unroll
        for (int r = 0; r < 4; ++r)
            bal[t][r] = __ballot(acc[r] > TAU);
    }
    if (l < 16) {
        // row within tile == l; its bits for reg r=l&3 live in lane-chunk q=l>>2
        int r = l & 3, qq = l >> 2;
        unsigned long long w = 0;
        #pragma unroll
        for (int t = 0; t < 4; ++t)
            w |= ((bal[t][r] >> (qq * 16)) & 0xFFFFull) << (t * 16);
        mask[((size_t)(b * NN + n0 + l)) * NWRD + blockIdx.y] = w;
    }
}

// ---------------- K3: deg -> dinv = 1/sqrt(deg) ---------------------------------
__global__ __launch_bounds__(256) void k_deg(const unsigned long long* __restrict__ mask,
                                             float* __restrict__ dinv) {
    int lane = threadIdx.x & 63;
    int gw = blockIdx.x * 4 + (threadIdx.x >> 6);   // row id
    unsigned long long w = mask[(size_t)gw * NWRD + lane];
    float cnt = (float)__popcll(w);
    #pragma unroll
    for (int off = 32; off; off >>= 1) cnt += __shfl_xor(cnt, off, 64);
    if (lane == 0) dinv[gw] = rsqrtf(cnt);
}

// ---------------- K4: pack y = dinv.*xin into MFMA b-frag order, hi/lo bf16 -----
// yp[b][kt][c*32 + kin] = bf16(y[kt*32+kin][c]); LDS transpose for coalescing.
__global__ __launch_bounds__(256) void k_pack(const float* __restrict__ xin,
                                              const float* __restrict__ dinv,
                                              unsigned short* __restrict__ yph,
                                              unsigned short* __restrict__ ypl) {
    __shared__ float lds[32 * 65];
    int t = threadIdx.x;
    int kt = blockIdx.x;                 // 0..127
    int b = blockIdx.y;
    size_t ibase = (size_t)b * NN * CC + (size_t)kt * 32 * CC;
    #pragma unroll
    for (int i = 0; i < 2; ++i) {
        int f4 = i * 256 + t;            // float4 index in [0, 512)
        int m = f4 >> 4;                 // 16 float4 per row
        float d = dinv[b * NN + kt * 32 + m];
        float4 v = ((const float4*)(xin + ibase))[f4];
        int c = (f4 & 15) * 4;
        lds[m * 65 + c + 0] = v.x * d;
        lds[m * 65 + c + 1] = v.y * d;
        lds[m * 65 + c + 2] = v.z * d;
        lds[m * 65 + c + 3] = v.w * d;
    }
    __syncthreads();
    size_t obase = (size_t)b * NN * CC + (size_t)kt * 2048;
    int kin = t & 31;
    int chi = t >> 5;                    // 0..7
    #pragma unroll
    for (int cg = 0; cg < 8; ++cg) {
        int c = cg * 8 + chi;
        float v = lds[kin * 65 + c];
        unsigned int hb = bf16_rne(v);
        float lo = v - __uint_as_float(hb << 16);
        unsigned int lb = bf16_rne(lo);
        yph[obase + c * 32 + kin] = (unsigned short)hb;
        ypl[obase + c * 32 + kin] = (unsigned short)lb;
    }
}

// ---------------- K5: MFMA diffusion GEMM + fused epilogue ----------------------
// 8 waves: waves 0-3 m in [0,2048), waves 4-7 m in [2048,4096); LDS partial sum.
__global__ __launch_bounds__(512) void k_gemm(const unsigned long long* __restrict__ mask,
                                              const unsigned short* __restrict__ yph,
                                              const unsigned short* __restrict__ ypl,
                                              const float* __restrict__ dinv,
                                              const float* __restrict__ W,
                                              float* __restrict__ out) {
    __shared__ float Ssh[2][64 * 64];
    int l = threadIdx.x & 63;
    int wv = threadIdx.x >> 6;
    int b = blockIdx.y;
    int n0 = blockIdx.x * 64;
    int nsub = wv & 3, half = wv >> 2;
    int q = l >> 4, lc = l & 15;
    int nrow = n0 + nsub * 16 + lc;
    const unsigned long long* mrow = mask + ((size_t)(b * NN + nrow)) * NWRD;
    const unsigned short* bh = yph + (size_t)b * NN * CC;
    const unsigned short* bl = ypl + (size_t)b * NN * CC;

    f32x4 acc[4] = {f32x4{0,0,0,0}, f32x4{0,0,0,0}, f32x4{0,0,0,0}, f32x4{0,0,0,0}};

    for (int w64 = half * 32; w64 < half * 32 + 32; ++w64) {
        unsigned long long mword = mrow[w64];
        #pragma unroll
        for (int h = 0; h < 2; ++h) {
            unsigned int bits = (unsigned int)(mword >> (h * 32 + q * 8)) & 0xFFu;
            union { unsigned int u[4]; short8 v; } ua;
            ua.u[0] = ((bits & 1u)   ? 0x3F80u : 0u) | ((bits & 2u)   ? 0x3F800000u : 0u);
            ua.u[1] = ((bits & 4u)   ? 0x3F80u : 0u) | ((bits & 8u)   ? 0x3F800000u : 0u);
            ua.u[2] = ((bits & 16u)  ? 0x3F80u : 0u) | ((bits & 32u)  ? 0x3F800000u : 0u);
            ua.u[3] = ((bits & 64u)  ? 0x3F80u : 0u) | ((bits & 128u) ? 0x3F800000u : 0u);
            short8 afrag = ua.v;
            int kt = w64 * 2 + h;
            size_t bof = (size_t)kt * 2048 + q * 8;
            short8 bfh[4], bfl[4];
            #pragma unroll
            for (int t = 0; t < 4; ++t)
                bfh[t] = *(const short8*)(bh + bof + (size_t)(t * 16 + lc) * 32);
            #pragma unroll
            for (int t = 0; t < 4; ++t)
                bfl[t] = *(const short8*)(bl + bof + (size_t)(t * 16 + lc) * 32);
            #pragma unroll
            for (int t = 0; t < 4; ++t)
                acc[t] = __builtin_amdgcn_mfma_f32_16x16x32_bf16(afrag, bfh[t], acc[t], 0, 0, 0);
            #pragma unroll
            for (int t = 0; t < 4; ++t)
                acc[t] = __builtin_amdgcn_mfma_f32_16x16x32_bf16(afrag, bfl[t], acc[t], 0, 0, 0);
        }
    }

    // C/D layout: col = lane&15, row = (lane>>4)*4 + reg
    #pragma unroll
    for (int t = 0; t < 4; ++t)
        #pragma unroll
        for (int r = 0; r < 4; ++r)
            Ssh[half][(nsub * 16 + q * 4 + r) * 64 + t * 16 + lc] = acc[t][r];

    float Wreg[64];
    #pragma unroll
    for (int c = 0; c < 64; ++c) Wreg[c] = W[c * 64 + l];
    __syncthreads();

    // epilogue: 8 rows per wave; lane = output feature
    for (int t = 0; t < 8; ++t) {
        int row = wv * 8 + t;
        int n = n0 + row;
        float dn = dinv[b * NN + n];
        float hsum = 0.f;
        #pragma unroll
        for (int c4 = 0; c4 < 16; ++c4) {
            float4 s0 = *(const float4*)&Ssh[0][row * 64 + c4 * 4];
            float4 s1 = *(const float4*)&Ssh[1][row * 64 + c4 * 4];
            hsum += (s0.x + s1.x) * Wreg[c4 * 4 + 0] + (s0.y + s1.y) * Wreg[c4 * 4 + 1]
                  + (s0.z + s1.z) * Wreg[c4 * 4 + 2] + (s0.w + s1.w) * Wreg[c4 * 4 + 3];
        }
        float hval = hsum * dn;
        float mean = hval;
        #pragma unroll
        for (int off = 32; off; off >>= 1) mean += __shfl_xor(mean, off, 64);
        mean *= (1.f / 64.f);
        float dv = hval - mean;
        float var = dv * dv;
        #pragma unroll
        for (int off = 32; off; off >>= 1) var += __shfl_xor(var, off, 64);
        var *= (1.f / 64.f);
        float o = dv * rsqrtf(var + EPSN);
        out[((size_t)(b * NN + n)) * CC + l] = o > 0.f ? o : 0.f;
    }
}

extern "C" void kernel_launch(void* const* d_in, const int* in_sizes, int n_in,
                              void* d_out, int out_size, void* d_ws, size_t ws_size,
                              hipStream_t stream) {
    const float* x  = (const float*)d_in[0];
    const float* W0 = (const float*)d_in[1];
    const float* W1 = (const float*)d_in[2];
    float* out = (float*)d_out;

    char* ws = (char*)d_ws;
    // Workspace layout (~24.1 MiB total)
    float* xt    = (float*)(ws);                                    // 4 MiB
    float* x2    = (float*)(ws + ((size_t)4  << 20));               // 4 MiB
    unsigned long long* mask = (unsigned long long*)(ws + ((size_t)8 << 20)); // 8 MiB
    unsigned short* yph = (unsigned short*)(ws + ((size_t)16 << 20));   // 2 MiB
    unsigned short* ypl = (unsigned short*)(ws + ((size_t)18 << 20));   // 2 MiB
    unsigned short* ynh = (unsigned short*)(ws + ((size_t)20 << 20));   // 2 MiB
    unsigned short* ynl = (unsigned short*)(ws + ((size_t)22 << 20));   // 2 MiB
    float* dinv  = (float*)(ws + ((size_t)24 << 20));               // 64 KiB

    // Build adjacency
    k_transpose<<<dim3(BB * NN / 4), 256, 0, stream>>>(x, xt, ynh, ynl);
    k_corr<<<dim3(64, 64, BB), 256, 0, stream>>>(ynh, ynl, mask);
    k_deg<<<dim3(BB * NN / 4), 256, 0, stream>>>(mask, dinv);

    // Layer 1
    k_pack<<<dim3(128, BB), 256, 0, stream>>>(xt, dinv, yph, ypl);
    k_gemm<<<dim3(NN / 64, BB), 512, 0, stream>>>(mask, yph, ypl, dinv, W0, x2);

    // Layer 2
    k_pack<<<dim3(128, BB), 256, 0, stream>>>(x2, dinv, yph, ypl);
    k_gemm<<<dim3(NN / 64, BB), 512, 0, stream>>>(mask, yph, ypl, dinv, W1, out);
}

// Round 4
// 351.403 us; speedup vs baseline: 3.4547x; 1.0861x over previous
//
#include <hip/hip_runtime.h>
#include <hip/hip_bf16.h>
#include <cstdint>

// Problem constants: B=4, C=feat=64, N=H*W=4096.
#define BB 4
#define CC 64
#define NN 4096
#define NWRD 64          // 4096 bits / 64 per mask row
#define TAU 0.005f
#define EPSN 1e-5f

typedef __attribute__((ext_vector_type(8))) short short8;   // 8 bf16 (4 VGPRs)
typedef __attribute__((ext_vector_type(4))) float f32x4;

__device__ inline unsigned int bf16_rne(float v) {
    unsigned int u = __float_as_uint(v);
    return (u + 0x7FFFu + ((u >> 16) & 1u)) >> 16;
}

// ---------------- K1: LDS-tiled transpose x[B][C][N] -> xt[B*N][C] + normalized bf16 hi/lo
__global__ __launch_bounds__(256) void k_transpose(const float* __restrict__ x,
                                                   float* __restrict__ xt,
                                                   unsigned short* __restrict__ ynh,
                                                   unsigned short* __restrict__ ynl) {
    __shared__ float lds[64 * 65];
    int t = threadIdx.x;
    int b = blockIdx.y;
    int n0 = blockIdx.x * 64;
    // load 64c x 64n tile, coalesced float4 along n
    #pragma unroll
    for (int i = 0; i < 4; ++i) {
        int c = i * 16 + (t >> 4);
        int nc = (t & 15) * 4;
        float4 v = *(const float4*)(x + ((size_t)(b * CC + c)) * NN + n0 + nc);
        lds[c * 65 + nc + 0] = v.x;
        lds[c * 65 + nc + 1] = v.y;
        lds[c * 65 + nc + 2] = v.z;
        lds[c * 65 + nc + 3] = v.w;
    }
    __syncthreads();
    int l = t & 63, wv = t >> 6;
    for (int i = 0; i < 16; ++i) {
        int n = wv * 16 + i;
        float v = lds[l * 65 + n];          // bank = (l+n)&31 -> conflict-free
        float s = v * v;
        #pragma unroll
        for (int off = 32; off; off >>= 1) s += __shfl_xor(s, off, 64);
        float yv = v * rsqrtf(s);
        unsigned int hb = bf16_rne(yv);
        float lo = yv - __uint_as_float(hb << 16);
        unsigned int lb = bf16_rne(lo);
        size_t row = (size_t)(b * NN + n0 + n);
        xt[row * CC + l] = v;
        ynh[row * CC + l] = (unsigned short)hb;
        ynl[row * CC + l] = (unsigned short)lb;
    }
}

// ---------------- K2: MFMA correlation -> binary adjacency bitmask --------------
// G = Yn*Yn^T via bf16 hi/lo split (hh + hl + lh). Wave: 16 n x 256 m strip.
__global__ __launch_bounds__(256) void k_corr(const unsigned short* __restrict__ ynh,
                                              const unsigned short* __restrict__ ynl,
                                              unsigned long long* __restrict__ mask) {
    int l = threadIdx.x & 63;
    int wv = threadIdx.x >> 6;
    int lc = l & 15, q = l >> 4;
    int b = blockIdx.z;
    int n0 = blockIdx.x * 64 + wv * 16;
    int m0 = blockIdx.y * 256;
    const unsigned short* baseH = ynh + (size_t)b * NN * CC;
    const unsigned short* baseL = ynl + (size_t)b * NN * CC;
    short8 ah[2], al[2];
    #pragma unroll
    for (int ks = 0; ks < 2; ++ks) {
        size_t off = (size_t)(n0 + lc) * CC + ks * 32 + q * 8;
        ah[ks] = *(const short8*)(baseH + off);
        al[ks] = *(const short8*)(baseL + off);
    }
    unsigned long long wout[4];
    #pragma unroll
    for (int tg = 0; tg < 4; ++tg) {
        unsigned long long bal[4][4];
        #pragma unroll
        for (int tt = 0; tt < 4; ++tt) {            // 4 independent MFMA chains in flight
            int t = tg * 4 + tt;
            f32x4 acc = {0.f, 0.f, 0.f, 0.f};
            #pragma unroll
            for (int ks = 0; ks < 2; ++ks) {
                size_t off = (size_t)(m0 + t * 16 + lc) * CC + ks * 32 + q * 8;
                short8 bh = *(const short8*)(baseH + off);
                short8 bl = *(const short8*)(baseL + off);
                acc = __builtin_amdgcn_mfma_f32_16x16x32_bf16(ah[ks], bh, acc, 0, 0, 0);
                acc = __builtin_amdgcn_mfma_f32_16x16x32_bf16(ah[ks], bl, acc, 0, 0, 0);
                acc = __builtin_amdgcn_mfma_f32_16x16x32_bf16(al[ks], bh, acc, 0, 0, 0);
            }
            #pragma unroll
            for (int r = 0; r < 4; ++r)
                bal[tt][r] = __ballot(acc[r] > TAU);
        }
        // row within tile == l (l<16); reg r=l&3, lane-chunk q=l>>2
        int r = l & 3, qq = (l >> 2) & 3;
        unsigned long long w = 0;
        #pragma unroll
        for (int tt = 0; tt < 4; ++tt)
            w |= ((bal[tt][r] >> (qq * 16)) & 0xFFFFull) << (tt * 16);
        wout[tg] = w;
    }
    if (l < 16) {
        #pragma unroll
        for (int tg = 0; tg < 4; ++tg)
            mask[((size_t)(b * NN + n0 + l)) * NWRD + blockIdx.y * 4 + tg] = wout[tg];
    }
}

// ---------------- K3: deg -> dinv = 1/sqrt(deg) ---------------------------------
__global__ __launch_bounds__(256) void k_deg(const unsigned long long* __restrict__ mask,
                                             float* __restrict__ dinv) {
    int lane = threadIdx.x & 63;
    int gw = blockIdx.x * 4 + (threadIdx.x >> 6);   // row id
    unsigned long long w = mask[(size_t)gw * NWRD + lane];
    float cnt = (float)__popcll(w);
    #pragma unroll
    for (int off = 32; off; off >>= 1) cnt += __shfl_xor(cnt, off, 64);
    if (lane == 0) dinv[gw] = rsqrtf(cnt);
}

// ---------------- K4: pack y = dinv.*xin into MFMA b-frag order, hi/lo bf16 -----
// yp[b][kt][c*32 + kin] = bf16(y[kt*32+kin][c]); LDS transpose for coalescing.
__global__ __launch_bounds__(256) void k_pack(const float* __restrict__ xin,
                                              const float* __restrict__ dinv,
                                              unsigned short* __restrict__ yph,
                                              unsigned short* __restrict__ ypl) {
    __shared__ float lds[32 * 65];
    int t = threadIdx.x;
    int kt = blockIdx.x;                 // 0..127
    int b = blockIdx.y;
    size_t ibase = (size_t)b * NN * CC + (size_t)kt * 32 * CC;
    #pragma unroll
    for (int i = 0; i < 2; ++i) {
        int f4 = i * 256 + t;            // float4 index in [0, 512)
        int m = f4 >> 4;                 // 16 float4 per row
        float d = dinv[b * NN + kt * 32 + m];
        float4 v = ((const float4*)(xin + ibase))[f4];
        int c = (f4 & 15) * 4;
        lds[m * 65 + c + 0] = v.x * d;
        lds[m * 65 + c + 1] = v.y * d;
        lds[m * 65 + c + 2] = v.z * d;
        lds[m * 65 + c + 3] = v.w * d;
    }
    __syncthreads();
    size_t obase = (size_t)b * NN * CC + (size_t)kt * 2048;
    int kin = t & 31;
    int chi = t >> 5;                    // 0..7
    #pragma unroll
    for (int cg = 0; cg < 8; ++cg) {
        int c = cg * 8 + chi;
        float v = lds[kin * 65 + c];
        unsigned int hb = bf16_rne(v);
        float lo = v - __uint_as_float(hb << 16);
        unsigned int lb = bf16_rne(lo);
        yph[obase + c * 32 + kin] = (unsigned short)hb;
        ypl[obase + c * 32 + kin] = (unsigned short)lb;
    }
}

// ---------------- K5: MFMA diffusion GEMM + fused epilogue ----------------------
// 8 waves = 2 n-subtiles x 4 m-quarters; 32 n rows per block; LDS partial sum.
#define SROW 68   // padded LDS row stride (floats): 16B-aligned, 2-way-max banks
__global__ __launch_bounds__(512) void k_gemm(const unsigned long long* __restrict__ mask,
                                              const unsigned short* __restrict__ yph,
                                              const unsigned short* __restrict__ ypl,
                                              const float* __restrict__ dinv,
                                              const float* __restrict__ W,
                                              float* __restrict__ out) {
    __shared__ float Ssh[4][32 * SROW];
    int l = threadIdx.x & 63;
    int wv = threadIdx.x >> 6;            // 0..7
    int b = blockIdx.y;
    int n0 = blockIdx.x * 32;
    int nsub = wv & 1, quar = wv >> 1;
    int q = l >> 4, lc = l & 15;
    int nrow = n0 + nsub * 16 + lc;
    const unsigned long long* mrow = mask + ((size_t)(b * NN + nrow)) * NWRD;
    const unsigned short* bh = yph + (size_t)b * NN * CC;
    const unsigned short* bl = ypl + (size_t)b * NN * CC;

    f32x4 acc[4] = {f32x4{0,0,0,0}, f32x4{0,0,0,0}, f32x4{0,0,0,0}, f32x4{0,0,0,0}};

    for (int w64 = quar * 16; w64 < quar * 16 + 16; ++w64) {
        unsigned long long mword = mrow[w64];
        #pragma unroll
        for (int h = 0; h < 2; ++h) {
            unsigned int bits = (unsigned int)(mword >> (h * 32 + q * 8)) & 0xFFu;
            union { unsigned int u[4]; short8 v; } ua;
            ua.u[0] = ((bits & 1u)   ? 0x3F80u : 0u) | ((bits & 2u)   ? 0x3F800000u : 0u);
            ua.u[1] = ((bits & 4u)   ? 0x3F80u : 0u) | ((bits & 8u)   ? 0x3F800000u : 0u);
            ua.u[2] = ((bits & 16u)  ? 0x3F80u : 0u) | ((bits & 32u)  ? 0x3F800000u : 0u);
            ua.u[3] = ((bits & 64u)  ? 0x3F80u : 0u) | ((bits & 128u) ? 0x3F800000u : 0u);
            short8 afrag = ua.v;
            int kt = w64 * 2 + h;
            size_t bof = (size_t)kt * 2048 + q * 8;
            short8 bfh[4], bfl[4];
            #pragma unroll
            for (int t = 0; t < 4; ++t)
                bfh[t] = *(const short8*)(bh + bof + (size_t)(t * 16 + lc) * 32);
            #pragma unroll
            for (int t = 0; t < 4; ++t)
                bfl[t] = *(const short8*)(bl + bof + (size_t)(t * 16 + lc) * 32);
            #pragma unroll
            for (int t = 0; t < 4; ++t)
                acc[t] = __builtin_amdgcn_mfma_f32_16x16x32_bf16(afrag, bfh[t], acc[t], 0, 0, 0);
            #pragma unroll
            for (int t = 0; t < 4; ++t)
                acc[t] = __builtin_amdgcn_mfma_f32_16x16x32_bf16(afrag, bfl[t], acc[t], 0, 0, 0);
        }
    }

    // C/D layout: col = lane&15, row = (lane>>4)*4 + reg
    #pragma unroll
    for (int t = 0; t < 4; ++t)
        #pragma unroll
        for (int r = 0; r < 4; ++r)
            Ssh[quar][(nsub * 16 + q * 4 + r) * SROW + t * 16 + lc] = acc[t][r];

    float Wreg[64];
    #pragma unroll
    for (int c = 0; c < 64; ++c) Wreg[c] = W[c * 64 + l];
    __syncthreads();

    // epilogue: 32 rows, 8 waves -> 4 rows/wave; lane = output feature
    for (int t = 0; t < 4; ++t) {
        int row = wv * 4 + t;
        int n = n0 + row;
        float dn = dinv[b * NN + n];
        float hsum = 0.f;
        #pragma unroll
        for (int c4 = 0; c4 < 16; ++c4) {
            float4 s0 = *(const float4*)&Ssh[0][row * SROW + c4 * 4];
            float4 s1 = *(const float4*)&Ssh[1][row * SROW + c4 * 4];
            float4 s2 = *(const float4*)&Ssh[2][row * SROW + c4 * 4];
            float4 s3 = *(const float4*)&Ssh[3][row * SROW + c4 * 4];
            hsum += (s0.x + s1.x + s2.x + s3.x) * Wreg[c4 * 4 + 0]
                  + (s0.y + s1.y + s2.y + s3.y) * Wreg[c4 * 4 + 1]
                  + (s0.z + s1.z + s2.z + s3.z) * Wreg[c4 * 4 + 2]
                  + (s0.w + s1.w + s2.w + s3.w) * Wreg[c4 * 4 + 3];
        }
        float hval = hsum * dn;
        float mean = hval;
        #pragma unroll
        for (int off = 32; off; off >>= 1) mean += __shfl_xor(mean, off, 64);
        mean *= (1.f / 64.f);
        float dv = hval - mean;
        float var = dv * dv;
        #pragma unroll
        for (int off = 32; off; off >>= 1) var += __shfl_xor(var, off, 64);
        var *= (1.f / 64.f);
        float o = dv * rsqrtf(var + EPSN);
        out[((size_t)(b * NN + n)) * CC + l] = o > 0.f ? o : 0.f;
    }
}

extern "C" void kernel_launch(void* const* d_in, const int* in_sizes, int n_in,
                              void* d_out, int out_size, void* d_ws, size_t ws_size,
                              hipStream_t stream) {
    const float* x  = (const float*)d_in[0];
    const float* W0 = (const float*)d_in[1];
    const float* W1 = (const float*)d_in[2];
    float* out = (float*)d_out;

    char* ws = (char*)d_ws;
    // Workspace layout (~24.1 MiB total)
    float* xt    = (float*)(ws);                                    // 4 MiB
    float* x2    = (float*)(ws + ((size_t)4  << 20));               // 4 MiB
    unsigned long long* mask = (unsigned long long*)(ws + ((size_t)8 << 20)); // 8 MiB
    unsigned short* yph = (unsigned short*)(ws + ((size_t)16 << 20));   // 2 MiB
    unsigned short* ypl = (unsigned short*)(ws + ((size_t)18 << 20));   // 2 MiB
    unsigned short* ynh = (unsigned short*)(ws + ((size_t)20 << 20));   // 2 MiB
    unsigned short* ynl = (unsigned short*)(ws + ((size_t)22 << 20));   // 2 MiB
    float* dinv  = (float*)(ws + ((size_t)24 << 20));               // 64 KiB

    // Build adjacency
    k_transpose<<<dim3(NN / 64, BB), 256, 0, stream>>>(x, xt, ynh, ynl);
    k_corr<<<dim3(64, 16, BB), 256, 0, stream>>>(ynh, ynl, mask);
    k_deg<<<dim3(BB * NN / 4), 256, 0, stream>>>(mask, dinv);

    // Layer 1
    k_pack<<<dim3(128, BB), 256, 0, stream>>>(xt, dinv, yph, ypl);
    k_gemm<<<dim3(NN / 32, BB), 512, 0, stream>>>(mask, yph, ypl, dinv, W0, x2);

    // Layer 2
    k_pack<<<dim3(128, BB), 256, 0, stream>>>(x2, dinv, yph, ypl);
    k_gemm<<<dim3(NN / 32, BB), 512, 0, stream>>>(mask, yph, ypl, dinv, W1, out);
}

// Round 5
// 178.392 us; speedup vs baseline: 6.8052x; 1.9698x over previous
//
#include <hip/hip_runtime.h>
#include <hip/hip_bf16.h>
#include <cstdint>

// Problem constants: B=4, C=feat=64, N=H*W=4096.
#define BB 4
#define CC 64
#define NN 4096
#define NWRD 64          // 4096 bits / 64 per mask row
#define TAU 0.005f
#define EPSN 1e-5f
#define MSPLITS 8

typedef __attribute__((ext_vector_type(8))) short short8;   // 8 bf16 (4 VGPRs)
typedef __attribute__((ext_vector_type(4))) float f32x4;
typedef unsigned long long ull;

__device__ inline unsigned int bf16_rne(float v) {
    unsigned int u = __float_as_uint(v);
    return (u + 0x7FFFu + ((u >> 16) & 1u)) >> 16;
}

// ---------------- K1: LDS-tiled transpose x[B][C][N] -> xt[B*N][C] + normalized bf16 hi/lo
__global__ __launch_bounds__(256) void k_transpose(const float* __restrict__ x,
                                                   float* __restrict__ xt,
                                                   unsigned short* __restrict__ ynh,
                                                   unsigned short* __restrict__ ynl) {
    __shared__ float lds[64 * 65];
    int t = threadIdx.x;
    int b = blockIdx.y;
    int n0 = blockIdx.x * 64;
    #pragma unroll
    for (int i = 0; i < 4; ++i) {
        int c = i * 16 + (t >> 4);
        int nc = (t & 15) * 4;
        float4 v = *(const float4*)(x + ((size_t)(b * CC + c)) * NN + n0 + nc);
        lds[c * 65 + nc + 0] = v.x;
        lds[c * 65 + nc + 1] = v.y;
        lds[c * 65 + nc + 2] = v.z;
        lds[c * 65 + nc + 3] = v.w;
    }
    __syncthreads();
    int l = t & 63, wv = t >> 6;
    for (int i = 0; i < 16; ++i) {
        int n = wv * 16 + i;
        float v = lds[l * 65 + n];
        float s = v * v;
        #pragma unroll
        for (int off = 32; off; off >>= 1) s += __shfl_xor(s, off, 64);
        float yv = v * rsqrtf(s);
        unsigned int hb = bf16_rne(yv);
        float lo = yv - __uint_as_float(hb << 16);
        unsigned int lb = bf16_rne(lo);
        size_t row = (size_t)(b * NN + n0 + n);
        xt[row * CC + l] = v;
        ynh[row * CC + l] = (unsigned short)hb;
        ynl[row * CC + l] = (unsigned short)lb;
    }
}

// ---------------- K2: MFMA correlation with LDS-staged B -------------------------
// Block: 4 waves x 32n = 128 n; sweeps 512 m in 4 chunks of 128 (hi+lo staged, swizzled).
#define CORR_MC 128
__global__ __launch_bounds__(256) void k_corr(const unsigned short* __restrict__ ynh,
                                              const unsigned short* __restrict__ ynl,
                                              ull* __restrict__ mask) {
    __shared__ unsigned short ldsH[CORR_MC * 64];
    __shared__ unsigned short ldsL[CORR_MC * 64];
    int t = threadIdx.x;
    int l = t & 63, wv = t >> 6;
    int lc = l & 15, q = l >> 4;
    int b = blockIdx.z;
    int n0 = blockIdx.x * 128 + wv * 32;
    int m0 = blockIdx.y * 512;
    const unsigned short* bH = ynh + (size_t)b * NN * CC;
    const unsigned short* bL = ynl + (size_t)b * NN * CC;

    // A-frags: 2 n-tiles x 2 k-sections, hi+lo (loaded once)
    short8 ah[2][2], al[2][2];
    #pragma unroll
    for (int nt = 0; nt < 2; ++nt)
        #pragma unroll
        for (int ks = 0; ks < 2; ++ks) {
            size_t off = (size_t)(n0 + nt * 16 + lc) * CC + (ks * 4 + q) * 8;
            ah[nt][ks] = *(const short8*)(bH + off);
            al[nt][ks] = *(const short8*)(bL + off);
        }

    // each lane <32 owns (ntile = l>>4, row rr = l&15); slice select indices
    int rr = l & 15;
    int rsel = rr & 3;            // which acc reg
    int qq = rr >> 2;             // which 16-bit slice of ballot
    bool nt1 = (l >> 4) & 1;      // lanes 16..31 own ntile1

    for (int mc = 0; mc < 4; ++mc) {
        __syncthreads();
        int mbase = m0 + mc * CORR_MC;
        #pragma unroll
        for (int rd = 0; rd < 4; ++rd) {
            int g = rd * 256 + t;             // 16B-chunk id 0..1023
            int row = g >> 3, c = g & 7;
            uint4 vh = *(const uint4*)(bH + (size_t)(mbase + row) * CC + c * 8);
            uint4 vl = *(const uint4*)(bL + (size_t)(mbase + row) * CC + c * 8);
            int sw = (c ^ (row & 7)) * 8;     // swizzle: ds_read bank floor
            *(uint4*)&ldsH[row * 64 + sw] = vh;
            *(uint4*)&ldsL[row * 64 + sw] = vl;
        }
        __syncthreads();
        ull w0 = 0, w1 = 0;
        #pragma unroll
        for (int tt = 0; tt < 8; ++tt) {
            short8 bh[2], bl[2];
            #pragma unroll
            for (int ks = 0; ks < 2; ++ks) {
                int rowm = tt * 16 + lc;
                int sw = ((ks * 4 + q) ^ (rowm & 7)) * 8;
                bh[ks] = *(const short8*)&ldsH[rowm * 64 + sw];
                bl[ks] = *(const short8*)&ldsL[rowm * 64 + sw];
            }
            ull bal[2][4];
            #pragma unroll
            for (int nt = 0; nt < 2; ++nt) {
                f32x4 acc = {0.f, 0.f, 0.f, 0.f};
                #pragma unroll
                for (int ks = 0; ks < 2; ++ks) {
                    acc = __builtin_amdgcn_mfma_f32_16x16x32_bf16(ah[nt][ks], bh[ks], acc, 0, 0, 0);
                    acc = __builtin_amdgcn_mfma_f32_16x16x32_bf16(ah[nt][ks], bl[ks], acc, 0, 0, 0);
                    acc = __builtin_amdgcn_mfma_f32_16x16x32_bf16(al[nt][ks], bh[ks], acc, 0, 0, 0);
                }
                #pragma unroll
                for (int r = 0; r < 4; ++r)
                    bal[nt][r] = __ballot(acc[r] > TAU);
            }
            // per-lane select of the ballot this lane's (ntile,row) needs
            ull s0a = (rsel & 1) ? bal[0][1] : bal[0][0];
            ull s0b = (rsel & 1) ? bal[0][3] : bal[0][2];
            ull s0  = (rsel & 2) ? s0b : s0a;
            ull s1a = (rsel & 1) ? bal[1][1] : bal[1][0];
            ull s1b = (rsel & 1) ? bal[1][3] : bal[1][2];
            ull s1  = (rsel & 2) ? s1b : s1a;
            ull sel = nt1 ? s1 : s0;
            ull part = ((sel >> (qq * 16)) & 0xFFFFull) << ((tt & 3) * 16);
            if (tt < 4) w0 |= part; else w1 |= part;
        }
        if (l < 32) {
            int row = n0 + (nt1 ? 16 : 0) + rr;
            int wbase = (mbase >> 6);
            mask[((size_t)(b * NN + row)) * NWRD + wbase + 0] = w0;
            mask[((size_t)(b * NN + row)) * NWRD + wbase + 1] = w1;
        }
    }
}

// ---------------- K3: deg -> dinv = 1/sqrt(deg) ---------------------------------
__global__ __launch_bounds__(256) void k_deg(const ull* __restrict__ mask,
                                             float* __restrict__ dinv) {
    int lane = threadIdx.x & 63;
    int gw = blockIdx.x * 4 + (threadIdx.x >> 6);
    ull w = mask[(size_t)gw * NWRD + lane];
    float cnt = (float)__popcll(w);
    #pragma unroll
    for (int off = 32; off; off >>= 1) cnt += __shfl_xor(cnt, off, 64);
    if (lane == 0) dinv[gw] = rsqrtf(cnt);
}

// ---------------- K4: pack y = dinv.*xin into MFMA b-frag (k-packed) order, bf16 hi
// yp[b][kt][c*32 + kin] = bf16(y[kt*32+kin][c]); LDS transpose for coalescing.
__global__ __launch_bounds__(256) void k_pack(const float* __restrict__ xin,
                                              const float* __restrict__ dinv,
                                              unsigned short* __restrict__ yph) {
    __shared__ float lds[32 * 65];
    int t = threadIdx.x;
    int kt = blockIdx.x;                 // 0..127
    int b = blockIdx.y;
    size_t ibase = (size_t)b * NN * CC + (size_t)kt * 32 * CC;
    #pragma unroll
    for (int i = 0; i < 2; ++i) {
        int f4 = i * 256 + t;
        int m = f4 >> 4;
        float d = dinv[b * NN + kt * 32 + m];
        float4 v = ((const float4*)(xin + ibase))[f4];
        int c = (f4 & 15) * 4;
        lds[m * 65 + c + 0] = v.x * d;
        lds[m * 65 + c + 1] = v.y * d;
        lds[m * 65 + c + 2] = v.z * d;
        lds[m * 65 + c + 3] = v.w * d;
    }
    __syncthreads();
    size_t obase = (size_t)b * NN * CC + (size_t)kt * 2048;
    int kin = t & 31;
    int chi = t >> 5;
    #pragma unroll
    for (int cg = 0; cg < 8; ++cg) {
        int c = cg * 8 + chi;
        yph[obase + c * 32 + kin] = (unsigned short)bf16_rne(lds[kin * 65 + c]);
    }
}

// ---------------- K5: MFMA diffusion GEMM, LDS-staged B, 8-way m-split ----------
// Block: 4 waves x 32n = 128 n; sweeps 512 m (one split) in 4 chunks of 128.
#define GMC 128
__global__ __launch_bounds__(256) void k_gemm(const ull* __restrict__ mask,
                                              const unsigned short* __restrict__ yph,
                                              float* __restrict__ plx) {
    __shared__ unsigned short ldsB[4 * 2048];   // 4 kt x 2048 = 16 KB
    int t = threadIdx.x;
    int l = t & 63, wv = t >> 6;
    int lc = l & 15, q = l >> 4;
    int b = blockIdx.z;
    int ms = blockIdx.y;                  // m-split 0..7
    int n0 = blockIdx.x * 128 + wv * 32;
    int m0 = ms * 512;
    const unsigned short* src = yph + (size_t)b * NN * CC;
    const ull* mrow0 = mask + ((size_t)(b * NN + n0 + lc)) * NWRD;
    const ull* mrow1 = mask + ((size_t)(b * NN + n0 + 16 + lc)) * NWRD;

    f32x4 acc[2][4];
    #pragma unroll
    for (int nt = 0; nt < 2; ++nt)
        #pragma unroll
        for (int tt = 0; tt < 4; ++tt) acc[nt][tt] = f32x4{0.f, 0.f, 0.f, 0.f};

    for (int mc = 0; mc < 4; ++mc) {
        __syncthreads();
        int ktbase = (m0 + mc * GMC) >> 5;          // global kt of chunk start
        #pragma unroll
        for (int rd = 0; rd < 4; ++rd) {
            int g = rd * 256 + t;                   // 16B chunk id 0..1023
            uint4 v = *(const uint4*)(src + (size_t)ktbase * 2048 + g * 8);
            *(uint4*)&ldsB[g * 8] = v;
        }
        __syncthreads();
        int wbase = (m0 + mc * GMC) >> 6;
        ull mw0a = mrow0[wbase], mw0b = mrow0[wbase + 1];
        ull mw1a = mrow1[wbase], mw1b = mrow1[wbase + 1];
        #pragma unroll
        for (int kt = 0; kt < 4; ++kt) {
            int sh = (kt & 1) * 32 + q * 8;
            unsigned int bits0 = (unsigned int)(((kt < 2) ? mw0a : mw0b) >> sh) & 0xFFu;
            unsigned int bits1 = (unsigned int)(((kt < 2) ? mw1a : mw1b) >> sh) & 0xFFu;
            union { unsigned int u[4]; short8 v; } a0, a1;
            #pragma unroll
            for (int j = 0; j < 4; ++j) {
                a0.u[j] = ((bits0 >> (2 * j)) & 1u ? 0x3F80u : 0u)
                        | ((bits0 >> (2 * j + 1)) & 1u ? 0x3F800000u : 0u);
                a1.u[j] = ((bits1 >> (2 * j)) & 1u ? 0x3F80u : 0u)
                        | ((bits1 >> (2 * j + 1)) & 1u ? 0x3F800000u : 0u);
            }
            #pragma unroll
            for (int tt = 0; tt < 4; ++tt) {
                short8 bf = *(const short8*)&ldsB[kt * 2048 + (tt * 16 + lc) * 32 + q * 8];
                acc[0][tt] = __builtin_amdgcn_mfma_f32_16x16x32_bf16(a0.v, bf, acc[0][tt], 0, 0, 0);
                acc[1][tt] = __builtin_amdgcn_mfma_f32_16x16x32_bf16(a1.v, bf, acc[1][tt], 0, 0, 0);
            }
        }
    }
    // store partials; D layout: col=lane&15, row=(lane>>4)*4+reg
    #pragma unroll
    for (int nt = 0; nt < 2; ++nt)
        #pragma unroll
        for (int tt = 0; tt < 4; ++tt)
            #pragma unroll
            for (int r = 0; r < 4; ++r) {
                int n = n0 + nt * 16 + q * 4 + r;
                int c = tt * 16 + lc;
                plx[((size_t)((ms * BB + b)) * NN + n) * CC + c] = acc[nt][tt][r];
            }
}

// ---------------- K6: reduce partials, *dinv_n, @W, instance norm, relu --------
__global__ __launch_bounds__(256) void k_out(const float* __restrict__ plx,
                                             const float* __restrict__ dinv,
                                             const float* __restrict__ W,
                                             float* __restrict__ xout) {
    __shared__ float Ws[64 * 64];
    __shared__ float lxs[4][64];
    int lane = threadIdx.x & 63;
    int wave = threadIdx.x >> 6;
    int b = blockIdx.y;
    int n0 = blockIdx.x * 64;
    for (int i = threadIdx.x; i < 64 * 64; i += 256) Ws[i] = W[i];
    __syncthreads();
    for (int tI = 0; tI < 16; ++tI) {
        int n = n0 + wave * 16 + tI;
        size_t row = (size_t)(b * NN + n);
        float lx = 0.f;
        #pragma unroll
        for (int s = 0; s < MSPLITS; ++s)
            lx += plx[((size_t)(s * BB + b) * NN + n) * CC + lane];
        lx *= dinv[row];
        lxs[wave][lane] = lx;
        float h = 0.f;
        #pragma unroll
        for (int c = 0; c < 64; ++c) h += lxs[wave][c] * Ws[c * 64 + lane];
        float mean = h;
        #pragma unroll
        for (int off = 32; off; off >>= 1) mean += __shfl_xor(mean, off, 64);
        mean *= (1.f / 64.f);
        float dv = h - mean;
        float var = dv * dv;
        #pragma unroll
        for (int off = 32; off; off >>= 1) var += __shfl_xor(var, off, 64);
        var *= (1.f / 64.f);
        float o = dv * rsqrtf(var + EPSN);
        xout[row * CC + lane] = o > 0.f ? o : 0.f;
    }
}

extern "C" void kernel_launch(void* const* d_in, const int* in_sizes, int n_in,
                              void* d_out, int out_size, void* d_ws, size_t ws_size,
                              hipStream_t stream) {
    const float* x  = (const float*)d_in[0];
    const float* W0 = (const float*)d_in[1];
    const float* W1 = (const float*)d_in[2];
    float* out = (float*)d_out;

    char* ws = (char*)d_ws;
    // Workspace layout (~54.1 MiB total)
    float* xt  = (float*)(ws);                                      // 4 MiB
    float* x2  = (float*)(ws + ((size_t)4  << 20));                 // 4 MiB
    ull* mask  = (ull*)(ws + ((size_t)8 << 20));                    // 8 MiB
    unsigned short* ynh = (unsigned short*)(ws + ((size_t)16 << 20)); // 2 MiB
    unsigned short* ynl = (unsigned short*)(ws + ((size_t)18 << 20)); // 2 MiB
    unsigned short* yph = (unsigned short*)(ws + ((size_t)20 << 20)); // 2 MiB
    float* plx = (float*)(ws + ((size_t)22 << 20));                 // 32 MiB
    float* dinv = (float*)(ws + ((size_t)54 << 20));                // 64 KiB

    // Build adjacency
    k_transpose<<<dim3(NN / 64, BB), 256, 0, stream>>>(x, xt, ynh, ynl);
    k_corr<<<dim3(NN / 128, NN / 512, BB), 256, 0, stream>>>(ynh, ynl, mask);
    k_deg<<<dim3(BB * NN / 4), 256, 0, stream>>>(mask, dinv);

    // Layer 1
    k_pack<<<dim3(128, BB), 256, 0, stream>>>(xt, dinv, yph);
    k_gemm<<<dim3(NN / 128, MSPLITS, BB), 256, 0, stream>>>(mask, yph, plx);
    k_out<<<dim3(NN / 64, BB), 256, 0, stream>>>(plx, dinv, W0, x2);

    // Layer 2
    k_pack<<<dim3(128, BB), 256, 0, stream>>>(x2, dinv, yph);
    k_gemm<<<dim3(NN / 128, MSPLITS, BB), 256, 0, stream>>>(mask, yph, plx);
    k_out<<<dim3(NN / 64, BB), 256, 0, stream>>>(plx, dinv, W1, out);
}